// Round 7
// baseline (193.211 us; speedup 1.0000x reference)
//
#include <hip/hip_runtime.h>
#include <math.h>

#define EPS 1e-5f

__device__ __forceinline__ float wave_sum(float v) {
  v += __shfl_down(v, 32);
  v += __shfl_down(v, 16);
  v += __shfl_down(v, 8);
  v += __shfl_down(v, 4);
  v += __shfl_down(v, 2);
  v += __shfl_down(v, 1);
  return v;
}

__device__ __forceinline__ float silu_f(float v) { return v / (1.f + __expf(-v)); }
__device__ __forceinline__ float sigm_f(float v) { return 1.f / (1.f + __expf(-v)); }

__device__ __forceinline__ int bitrev6(int v) {
  return ((v & 1) << 5) | ((v & 2) << 3) | ((v & 4) << 1) |
         ((v & 8) >> 1) | ((v & 16) >> 3) | ((v & 32) >> 5);
}

#define FFT6(zr, zi)                                           \
  do {                                                         \
    _Pragma("unroll") for (int s = 0; s < 6; ++s) {            \
      const int half = 32 >> s;                                \
      const bool up = (lane & half) != 0;                      \
      float pr = __shfl_xor(zr, half);                         \
      float pi = __shfl_xor(zi, half);                         \
      float tr = up ? pr - zr : zr + pr;                       \
      float ti = up ? pi - zi : zi + pi;                       \
      const float c = twc[s], sn = tws[s];                     \
      zr = tr * c - ti * sn;                                   \
      zi = tr * sn + ti * c;                                   \
    }                                                          \
  } while (0)

// ---------------------------------------------------------------------------
// Kernel A: per-(b,c) mean |2D-DFT| + spatial mean (R5 FFT), with the
// channel-attention head FUSED as a last-block-per-batch tail (threadfence +
// device-scope atomic counter; counter zeroed by hipMemsetAsync each call).
// Tail reuses re1[] as its scratch. Produces s2[b,c] directly.
// ---------------------------------------------------------------------------
__global__ __launch_bounds__(256) void k_dft(
    const float* __restrict__ x, float* __restrict__ energy,
    float* __restrict__ meanx, int* __restrict__ cnt,
    const float* __restrict__ ex_w, const float* __restrict__ ey_w,
    const float* __restrict__ ez_w, const float* __restrict__ ff_w,
    const float* __restrict__ ff_b, const float* __restrict__ g1_w,
    const float* __restrict__ g1_b, const float* __restrict__ g2_w,
    const float* __restrict__ g2_b, float* __restrict__ s2) {
  __shared__ float re1[33 * 65];   // [kv 0..32][h]; reused by attn tail
  __shared__ float im1[33 * 65];
  __shared__ float redA[4], redB[4];
  __shared__ int isLast;
  const int bc = blockIdx.x;       // b*64 + c
  const int tid = threadIdx.x;
  const int lane = tid & 63;
  const int wv = tid >> 6;         // wave 0..3
  const float* xp = x + (size_t)bc * 4096;

  float twc[6], tws[6];
#pragma unroll
  for (int s = 0; s < 6; ++s) {
    int half = 32 >> s;
    if (lane & half) {
      float ang = -6.283185307179586f * (float)((lane & (half - 1)) << s) / 64.f;
      float sv, cv;
      __sincosf(ang, &sv, &cv);
      twc[s] = cv;
      tws[s] = sv;
    } else {
      twc[s] = 1.f;
      tws[s] = 0.f;
    }
  }

  const int f = bitrev6(lane);
  const int fm = (64 - f) & 63;
  const int plane = bitrev6(fm);

  // ---- row pass: 4 rows per iter as 2 independent packed complex FFTs ----
  float lsum = 0.f;
#pragma unroll 1
  for (int rp = 0; rp < 4; ++rp) {
    const int h0 = wv * 16 + rp * 4;
    float x0 = xp[h0 * 64 + lane];
    float x1 = xp[(h0 + 1) * 64 + lane];
    float x2 = xp[(h0 + 2) * 64 + lane];
    float x3 = xp[(h0 + 3) * 64 + lane];
    lsum += x0 + x1 + x2 + x3;
    float zr = x0, zi = x1, yr = x2, yi = x3;
#pragma unroll
    for (int s = 0; s < 6; ++s) {
      const int half = 32 >> s;
      const bool up = (lane & half) != 0;
      float pzr = __shfl_xor(zr, half);
      float pzi = __shfl_xor(zi, half);
      float pyr = __shfl_xor(yr, half);
      float pyi = __shfl_xor(yi, half);
      float tzr = up ? pzr - zr : zr + pzr;
      float tzi = up ? pzi - zi : zi + pzi;
      float tyr = up ? pyr - yr : yr + pyr;
      float tyi = up ? pyi - yi : yi + pyi;
      const float c = twc[s], sn = tws[s];
      zr = tzr * c - tzi * sn;
      zi = tzr * sn + tzi * c;
      yr = tyr * c - tyi * sn;
      yi = tyr * sn + tyi * c;
    }
    float mzr = __shfl(zr, plane), mzi = __shfl(zi, plane);
    float myr = __shfl(yr, plane), myi = __shfl(yi, plane);
    if (f <= 32) {
      float ar = 0.5f * (zr + mzr), ai = 0.5f * (zi - mzi);
      float br = 0.5f * (zi + mzi), bi = 0.5f * (mzr - zr);
      float cr = 0.5f * (yr + myr), ci = 0.5f * (yi - myi);
      float dr = 0.5f * (yi + myi), di = 0.5f * (myr - yr);
      re1[f * 65 + h0] = ar;     im1[f * 65 + h0] = ai;
      re1[f * 65 + h0 + 1] = br; im1[f * 65 + h0 + 1] = bi;
      re1[f * 65 + h0 + 2] = cr; im1[f * 65 + h0 + 2] = ci;
      re1[f * 65 + h0 + 3] = dr; im1[f * 65 + h0 + 3] = di;
    }
  }
  __syncthreads();

  // ---- column pass: kv=0..31 as 2 independent chains/iter; kv=32 tail ----
  float msum = 0.f;
#pragma unroll 1
  for (int i = 0; i < 4; ++i) {
    const int kv1 = wv + 8 * i;
    const int kv2 = kv1 + 4;
    const float w1 = (kv1 == 0) ? 1.f : 2.f;
    float ar = re1[kv1 * 65 + lane];
    float ai = im1[kv1 * 65 + lane];
    float br = re1[kv2 * 65 + lane];
    float bi = im1[kv2 * 65 + lane];
#pragma unroll
    for (int s = 0; s < 6; ++s) {
      const int half = 32 >> s;
      const bool up = (lane & half) != 0;
      float par = __shfl_xor(ar, half);
      float pai = __shfl_xor(ai, half);
      float pbr = __shfl_xor(br, half);
      float pbi = __shfl_xor(bi, half);
      float tar = up ? par - ar : ar + par;
      float tai = up ? pai - ai : ai + pai;
      float tbr = up ? pbr - br : br + pbr;
      float tbi = up ? pbi - bi : bi + pbi;
      const float c = twc[s], sn = tws[s];
      ar = tar * c - tai * sn;
      ai = tar * sn + tai * c;
      br = tbr * c - tbi * sn;
      bi = tbr * sn + tbi * c;
    }
    msum += w1 * sqrtf(ar * ar + ai * ai) + 2.f * sqrtf(br * br + bi * bi);
  }
  if (wv == 0) {
    float ar = re1[32 * 65 + lane];
    float ai = im1[32 * 65 + lane];
    FFT6(ar, ai);
    msum += sqrtf(ar * ar + ai * ai);
  }

  msum = wave_sum(msum);
  lsum = wave_sum(lsum);
  if (lane == 0) { redA[wv] = msum; redB[wv] = lsum; }
  __syncthreads();
  if (tid == 0) {
    float e = redA[0] + redA[1] + redA[2] + redA[3];
    float m = redB[0] + redB[1] + redB[2] + redB[3];
    energy[bc] = e * (1.f / 4096.f);
    meanx[bc] = m * (1.f / 4096.f);
  }

  // ---- fused attention tail: last block of this batch does the head ----
  if (tid == 0) {
    __threadfence();                       // release energy/meanx
    int old = atomicAdd(&cnt[bc >> 6], 1); // device-scope
    isLast = (old == 63) ? 1 : 0;
  }
  __syncthreads();
  if (!isLast) return;
  __threadfence();                         // order loads after the atomic

  const int b = bc >> 6;
  float* e  = &re1[0];
  float* mx = &re1[64];
  float* my = &re1[128];
  float* mz = &re1[192];
  float* ax = &re1[256];
  float* ay = &re1[320];
  float* az = &re1[384];
  float* af = &re1[448];
  float* h1 = &re1[512];
  const int c = tid;                       // only c<64 active per stage
  if (c < 64) {
    e[c] = energy[b * 64 + c];
    mx[c] = meanx[b * 64 + c];
  }
  __syncthreads();
  if (c < 64) {
    int rank = 0;
    float ec = e[c];
    for (int i = 0; i < 64; ++i) {
      float ei = e[i];
      rank += (ei > ec) || (ei == ec && i < c);
    }
    float mask = (rank < 32) ? 1.f : 0.f;
    my[c] = mx[c] * mask;
    mz[c] = mx[c] * (1.f - mask);
  }
  __syncthreads();
  if (c < 64) {
    float l, r, m;
    l = (c > 0) ? mx[c - 1] : 0.f; m = mx[c]; r = (c < 63) ? mx[c + 1] : 0.f;
    ax[c] = sigm_f(ex_w[0] * l + ex_w[1] * m + ex_w[2] * r);
    l = (c > 0) ? my[c - 1] : 0.f; m = my[c]; r = (c < 63) ? my[c + 1] : 0.f;
    ay[c] = sigm_f(ey_w[0] * l + ey_w[1] * m + ey_w[2] * r);
    l = (c > 0) ? mz[c - 1] : 0.f; m = mz[c]; r = (c < 63) ? mz[c + 1] : 0.f;
    az[c] = sigm_f(ez_w[0] * l + ez_w[1] * m + ez_w[2] * r);
  }
  __syncthreads();
  if (c < 64) {
    int gg = c >> 4;
    float acc = ff_b[c];
#pragma unroll
    for (int i = 0; i < 32; ++i) {
      int ch = gg * 32 + i;
      float v = (ch < 64) ? ay[ch] : az[ch - 64];
      acc = fmaf(v, ff_w[c * 32 + i], acc);
    }
    af[c] = acc;
  }
  __syncthreads();
  if (c < 16) {
    float a = g1_b[c];
#pragma unroll
    for (int i = 0; i < 64; ++i) a = fmaf(af[i], g1_w[c * 128 + i], a);
#pragma unroll
    for (int i = 0; i < 64; ++i) a = fmaf(ax[i], g1_w[c * 128 + 64 + i], a);
    h1[c] = silu_f(a);
  }
  __syncthreads();
  if (c < 64) {
    float gv = g2_b[c];
#pragma unroll
    for (int o = 0; o < 16; ++o) gv = fmaf(h1[o], g2_w[c * 16 + o], gv);
    gv = sigm_f(gv);
    s2[b * 64 + c] = gv * af[c] + (1.f - gv) * ax[c];
  }
}

// ---------------------------------------------------------------------------
// Kernel C: fused ReceptiveFieldAttentionConv.
// R6: P=4 pixels/thread x icg-split-4. Each of the 4 waves handles the SAME
// 4-row band with its own icg quartet -> total LDS-broadcast b128 reads
// HALVE vs R5 at constant wave count (2048 = 8/CU). Two-stage stride-65 LDS
// merge; epilogue split across waves 0 (pixels 0,1) and 1 (pixels 2,3).
// a[] recomputed (not stored) to hold VGPRs ~170.
// ---------------------------------------------------------------------------
__global__ __launch_bounds__(256, 2) void k_rfa(
    const float* __restrict__ x,
    const float* __restrict__ sc_w, const float* __restrict__ sc_b,
    const float* __restrict__ ac_w, const float* __restrict__ ac_b,
    const float* __restrict__ oc_w, const float* __restrict__ oc_b,
    const float* __restrict__ bn_g, const float* __restrict__ bn_b,
    const float* __restrict__ bn_m, const float* __restrict__ bn_v,
    float* __restrict__ xrfa) {
  __shared__ __align__(16) float scwp[16 * 9 * 12];    // taps 0..8, bias at [9]
  __shared__ __align__(16) float mp[16 * 24];          // acw [0..8], acb [12..20]
  __shared__ __align__(16) float ocwp[16 * 16 * 12];
  __shared__ float red[2 * 64 * 65];                   // 33.3 KB merge buffer
  const int blk = blockIdx.x;          // 512 blocks: 16 bands x 4 g x 8 b
  const int band = blk & 15;
  const int g = (blk >> 4) & 3;
  const int b = blk >> 6;
  const int tid = threadIdx.x;
  const int lane = tid & 63;
  const int wv = tid >> 6;             // 0..3 = icg quartet

  // ---- stage packed weights (full 16-icg set, once per block) ----
  for (int i = tid; i < 1296; i += 256) {
    int icg = i / 81, rem = i - icg * 81;
    int j = rem / 9, t = rem - j * 9;
    scwp[icg * 108 + j * 12 + t] = sc_w[(g * 144 + icg * 9 + j) * 9 + t];
  }
  if (tid < 144) {
    int icg = tid / 9, j = tid - icg * 9;
    scwp[icg * 108 + j * 12 + 9] = sc_b[g * 144 + tid];
    mp[icg * 24 + j] = ac_w[g * 144 + tid];
    mp[icg * 24 + 12 + j] = ac_b[g * 144 + tid];
  }
  for (int i = tid; i < 2304; i += 256) {
    int oco = i / 144, rem = i - oco * 144;
    int icg = rem / 9, j = rem - icg * 9;
    ocwp[icg * 192 + oco * 12 + j] = oc_w[((g * 16 + oco) * 16 + icg) * 9 + j];
  }
  __syncthreads();

  const int r0 = band * 4;
  const int w = lane;
  const bool vW = w > 0, vE = w < 63;
  float acc[64];                        // [p*16 + oco]
#pragma unroll
  for (int i = 0; i < 64; ++i) acc[i] = 0.f;

  const float* xg = x + ((size_t)(b * 64 + g * 16)) * 4096 + w;
  const int icg0 = wv * 4;

#pragma unroll 1
  for (int ii = 0; ii < 4; ++ii) {
    const int icg = icg0 + ii;
    const float* xc = xg + icg * 4096;
    float n[18];                        // rows r0-1 .. r0+4, cols -1..1
#pragma unroll
    for (int t = 0; t < 6; ++t) {
      int h = r0 - 1 + t;
      bool vh = (h >= 0) && (h < 64);
      const float* row = xc + h * 64;
      n[t * 3 + 0] = (vh && vW) ? row[-1] : 0.f;
      n[t * 3 + 1] = vh ? row[0] : 0.f;
      n[t * 3 + 2] = (vh && vE) ? row[1] : 0.f;
    }
    float rs[6];
#pragma unroll
    for (int t = 0; t < 6; ++t) rs[t] = n[t * 3] + n[t * 3 + 1] + n[t * 3 + 2];
    float ap[4];
#pragma unroll
    for (int p = 0; p < 4; ++p) ap[p] = (rs[p] + rs[p + 1] + rs[p + 2]) * (1.f / 9.f);

    float aw[12], ab[12];
    *(float4*)&aw[0] = *(const float4*)&mp[icg * 24];
    *(float4*)&aw[4] = *(const float4*)&mp[icg * 24 + 4];
    *(float4*)&aw[8] = *(const float4*)&mp[icg * 24 + 8];
    *(float4*)&ab[0] = *(const float4*)&mp[icg * 24 + 12];
    *(float4*)&ab[4] = *(const float4*)&mp[icg * 24 + 16];
    *(float4*)&ab[8] = *(const float4*)&mp[icg * 24 + 20];

    float f[4][9];
    float amax[4] = {-1e30f, -1e30f, -1e30f, -1e30f};
#pragma unroll
    for (int j = 0; j < 9; ++j) {
      float wt[12];
      *(float4*)&wt[0] = *(const float4*)&scwp[icg * 108 + j * 12];
      *(float4*)&wt[4] = *(const float4*)&scwp[icg * 108 + j * 12 + 4];
      *(float4*)&wt[8] = *(const float4*)&scwp[icg * 108 + j * 12 + 8];
#pragma unroll
      for (int p = 0; p < 4; ++p) {
        float pre = wt[9];
#pragma unroll
        for (int t = 0; t < 9; ++t) pre = fmaf(n[p * 3 + t], wt[t], pre);
        f[p][j] = silu_f(pre);
        float av = fmaf(ap[p], aw[j], ab[j]);
        amax[p] = fmaxf(amax[p], av);
      }
    }
    float es[4] = {0.f, 0.f, 0.f, 0.f};
#pragma unroll
    for (int j = 0; j < 9; ++j) {
#pragma unroll
      for (int p = 0; p < 4; ++p) {
        float av = fmaf(ap[p], aw[j], ab[j]);     // recompute (saves 36 VGPRs)
        float ev = __expf(av - amax[p]);
        es[p] += ev;
        f[p][j] *= ev;                            // f now holds unnormalized P
      }
    }
#pragma unroll
    for (int p = 0; p < 4; ++p) {
      float inv = __fdividef(1.f, es[p]);
#pragma unroll
      for (int j = 0; j < 9; ++j) f[p][j] *= inv;
    }

#pragma unroll
    for (int oco = 0; oco < 16; ++oco) {
      float ov[12];
      *(float4*)&ov[0] = *(const float4*)&ocwp[icg * 192 + oco * 12];
      *(float4*)&ov[4] = *(const float4*)&ocwp[icg * 192 + oco * 12 + 4];
      *(float4*)&ov[8] = *(const float4*)&ocwp[icg * 192 + oco * 12 + 8];
#pragma unroll
      for (int p = 0; p < 4; ++p) {
        float s = 0.f;
#pragma unroll
        for (int j = 0; j < 9; ++j) s = fmaf(f[p][j], ov[j], s);
        acc[p * 16 + oco] += s;
      }
    }
  }

  // ---- two-stage merge of the 4 icg quartets (stride-65: 2-way, free) ----
  if (wv >= 2) {
    float* rp = &red[(wv - 2) * 64 * 65 + lane * 65];
#pragma unroll
    for (int k = 0; k < 64; ++k) rp[k] = acc[k];
  }
  __syncthreads();
  if (wv < 2) {
    const float* rp = &red[wv * 64 * 65 + lane * 65];
#pragma unroll
    for (int k = 0; k < 64; ++k) acc[k] += rp[k];
  }
  __syncthreads();
  if (wv == 1) {
    float* rp = &red[lane * 65];
#pragma unroll
    for (int k = 0; k < 32; ++k) rp[k] = acc[k];
  } else if (wv == 0) {
    float* rp = &red[64 * 65 + lane * 65];
#pragma unroll
    for (int k = 0; k < 32; ++k) rp[k] = acc[32 + k];
  }
  __syncthreads();

  if (wv < 2) {
    const int pbase = wv * 2;           // wave0 -> pixels 0,1 ; wave1 -> 2,3
    float av[32];
    if (wv == 0) {
      const float* rp = &red[lane * 65];
#pragma unroll
      for (int k = 0; k < 32; ++k) av[k] = acc[k] + rp[k];
    } else {
      const float* rp = &red[64 * 65 + lane * 65];
#pragma unroll
      for (int k = 0; k < 32; ++k) av[k] = acc[32 + k] + rp[k];
    }
    float* op = xrfa + ((size_t)(b * 64 + g * 16)) * 4096 + (r0 + pbase) * 64 + w;
#pragma unroll
    for (int oco = 0; oco < 16; ++oco) {
      int oc = g * 16 + oco;
      float s = bn_g[oc] * rsqrtf(bn_v[oc] + EPS);
      float bb = bn_b[oc] - bn_m[oc] * s;
      float ob = oc_b[oc];
      float v0 = fmaf(av[oco] + ob, s, bb);
      float v1 = fmaf(av[16 + oco] + ob, s, bb);
      op[oco * 4096] = silu_f(v0);
      op[oco * 4096 + 64] = silu_f(v1);
    }
  }
}

// ---------------------------------------------------------------------------
// Kernel D: final 1x1 conv + BN + SiLU (R5 oc-split, unchanged).
// ---------------------------------------------------------------------------
__global__ __launch_bounds__(256) void k_fuse(
    const float* __restrict__ x, const float* __restrict__ xrfa,
    const float* __restrict__ s2, const float* __restrict__ fu_w,
    const float* __restrict__ fu_b, const float* __restrict__ bn_g,
    const float* __restrict__ bn_b, const float* __restrict__ bn_m,
    const float* __restrict__ bn_v, float* __restrict__ out) {
  __shared__ __align__(16) float fw[4096];
  __shared__ float s2l[64];
  const int blk = blockIdx.x;          // 512 blocks
  const int tid = threadIdx.x;
  const int sloc = tid & 63;
  const int ocq = tid >> 6;            // oc octet 0..3
  const int b = blk >> 6;
  const int sp = (blk & 63) * 64 + sloc;

  for (int i = tid; i < 1024; i += 256)
    ((float4*)fw)[i] = ((const float4*)fu_w)[i];
  if (tid < 64) s2l[tid] = s2[b * 64 + tid];

  const float* xr = xrfa + (size_t)b * 64 * 4096 + sp;
  const float* xp = x + (size_t)b * 64 * 4096 + sp;
  float va[64], vb[64];
#pragma unroll
  for (int i = 0; i < 64; ++i) va[i] = xr[i * 4096];
#pragma unroll
  for (int i = 0; i < 64; ++i) vb[i] = xp[i * 4096];
  __syncthreads();
#pragma unroll
  for (int i = 0; i < 64; ++i) vb[i] *= s2l[i];

  float* op = out + (size_t)b * 32 * 4096 + sp;
#pragma unroll 1
  for (int o = 0; o < 8; ++o) {
    const int oc = ocq * 8 + o;
    const float* wr = &fw[oc * 128];
    float a = 0.f;
#pragma unroll
    for (int q = 0; q < 16; ++q) {
      float4 w4 = *(const float4*)&wr[q * 4];
      a = fmaf(va[q * 4 + 0], w4.x, a);
      a = fmaf(va[q * 4 + 1], w4.y, a);
      a = fmaf(va[q * 4 + 2], w4.z, a);
      a = fmaf(va[q * 4 + 3], w4.w, a);
    }
#pragma unroll
    for (int q = 0; q < 16; ++q) {
      float4 w4 = *(const float4*)&wr[64 + q * 4];
      a = fmaf(vb[q * 4 + 0], w4.x, a);
      a = fmaf(vb[q * 4 + 1], w4.y, a);
      a = fmaf(vb[q * 4 + 2], w4.z, a);
      a = fmaf(vb[q * 4 + 3], w4.w, a);
    }
    float s = bn_g[oc] * rsqrtf(bn_v[oc] + EPS);
    float v = a + fu_b[oc];
    v = fmaf(v, s, bn_b[oc] - bn_m[oc] * s);
    op[oc * 4096] = silu_f(v);
  }
}

extern "C" void kernel_launch(void* const* d_in, const int* in_sizes, int n_in,
                              void* d_out, int out_size, void* d_ws, size_t ws_size,
                              hipStream_t stream) {
  const float* x       = (const float*)d_in[0];
  const float* sc_w    = (const float*)d_in[1];
  const float* sc_b    = (const float*)d_in[2];
  const float* ac_w    = (const float*)d_in[3];
  const float* ac_b    = (const float*)d_in[4];
  const float* oc_w    = (const float*)d_in[5];
  const float* oc_b    = (const float*)d_in[6];
  const float* oc_bn_g = (const float*)d_in[7];
  const float* oc_bn_b = (const float*)d_in[8];
  const float* oc_bn_m = (const float*)d_in[9];
  const float* oc_bn_v = (const float*)d_in[10];
  const float* ex_w    = (const float*)d_in[11];
  const float* ey_w    = (const float*)d_in[12];
  const float* ez_w    = (const float*)d_in[13];
  const float* ff_w    = (const float*)d_in[14];
  const float* ff_b    = (const float*)d_in[15];
  const float* g1_w    = (const float*)d_in[16];
  const float* g1_b    = (const float*)d_in[17];
  const float* g2_w    = (const float*)d_in[18];
  const float* g2_b    = (const float*)d_in[19];
  const float* fu_w    = (const float*)d_in[20];
  const float* fu_b    = (const float*)d_in[21];
  const float* fu_bn_g = (const float*)d_in[22];
  const float* fu_bn_b = (const float*)d_in[23];
  const float* fu_bn_m = (const float*)d_in[24];
  const float* fu_bn_v = (const float*)d_in[25];

  float* ws     = (float*)d_ws;
  float* energy = ws;            // 512 floats
  float* meanx  = ws + 512;      // 512 floats
  float* s2     = ws + 1024;     // 512 floats
  int*   cnt    = (int*)(ws + 1536);  // 8 ints (zeroed below)
  float* xrfa   = ws + 2048;     // 8*64*4096 floats

  hipMemsetAsync(cnt, 0, 8 * sizeof(int), stream);
  k_dft<<<512, 256, 0, stream>>>(x, energy, meanx, cnt,
                                 ex_w, ey_w, ez_w, ff_w, ff_b,
                                 g1_w, g1_b, g2_w, g2_b, s2);
  k_rfa<<<512, 256, 0, stream>>>(x, sc_w, sc_b, ac_w, ac_b, oc_w, oc_b,
                                 oc_bn_g, oc_bn_b, oc_bn_m, oc_bn_v, xrfa);
  k_fuse<<<512, 256, 0, stream>>>(x, xrfa, s2, fu_w, fu_b,
                                  fu_bn_g, fu_bn_b, fu_bn_m, fu_bn_v,
                                  (float*)d_out);
}